// Round 1
// baseline (732.463 us; speedup 1.0000x reference)
//
#include <hip/hip_runtime.h>

// Capsule dynamic routing, MI355X (gfx950).
// Shapes: x (256,1152,8) f32, W (1152,8,10,16) f32, out v (256,10,16) f32.
// Strategy: never materialize u_hat (189MB). 3 routing passes recompute
// u_hat from LDS-staged W chunks. b-logits recomputed from saved v0/v1
// (b_iter2 = agr(v0)+agr(v1)) so no logit tensor. ws use: 480KB.

#define NUM_IN 1152
#define IN_DIM 8
#define NUM_OUT 10
#define OUT_DIM 16
#define BATCH 256
#define ICHUNK 16
#define NCHUNK (NUM_IN / ICHUNK)   // 72
#define BTILE 16
#define NBT (BATCH / BTILE)        // 16
#define SLOTS (NUM_OUT * OUT_DIM)  // 160

// Sum over the 16 contiguous lanes of a DPP "row" via row_ror rotations.
// All lanes end with the full row sum. Requires all 64 lanes active.
__device__ __forceinline__ float rowsum16(float x) {
  int v;
  v = __builtin_amdgcn_update_dpp(0, __float_as_int(x), 0x128, 0xF, 0xF, true); // ror:8
  x += __int_as_float(v);
  v = __builtin_amdgcn_update_dpp(0, __float_as_int(x), 0x124, 0xF, 0xF, true); // ror:4
  x += __int_as_float(v);
  v = __builtin_amdgcn_update_dpp(0, __float_as_int(x), 0x122, 0xF, 0xF, true); // ror:2
  x += __int_as_float(v);
  v = __builtin_amdgcn_update_dpp(0, __float_as_int(x), 0x121, 0xF, 0xF, true); // ror:1
  x += __int_as_float(v);
  return x;
}

// One routing pass. PASS=0: uniform c=0.1. PASS=1: c=softmax(agr(v0)).
// PASS=2: c=softmax(agr(v0)+agr(v1)). Accumulates s[b][j][o] via atomics.
template <int PASS>
__global__ __launch_bounds__(512) void caps_pass(
    const float* __restrict__ x, const float* __restrict__ W,
    const float* __restrict__ v0, const float* __restrict__ v1,
    float* __restrict__ s_out) {
  // W chunk for 16 input capsules, laid out [d][j][i_sub][o] so that for a
  // fixed (d,j) the wave's 64 float4 reads cover one contiguous 1KB block
  // (permuted by lane) -> conflict-free ds_read_b128.
  __shared__ float Ws[IN_DIM * NUM_OUT * ICHUNK * OUT_DIM];  // 80 KB

  const int t = threadIdx.x;
  const int ic = blockIdx.x % NCHUNK;
  const int bt = blockIdx.x / NCHUNK;
  const int i0 = ic * ICHUNK;

  // Cooperative stage: global W[(i0+i)*1280 + d*160 + j*16 + o]
  //                  -> Ws[((d*10+j)*16 + i)*16 + o], float4 granularity.
  for (int q = t; q < (ICHUNK * 1280) / 4; q += 512) {
    const int idx = q * 4;
    const int i = idx / 1280;
    const int rem = idx % 1280;          // d*160 + j*16 + o
    const int d = rem / 160;
    const int jo = rem % 160;
    const int j = jo >> 4;
    const int o = jo & 15;
    const float4 w =
        *reinterpret_cast<const float4*>(W + (size_t)(i0 + i) * 1280 + rem);
    *reinterpret_cast<float4*>(Ws + (d * 10 + j) * 256 + i * 16 + o) = w;
  }
  __syncthreads();

  const int lane = t & 63;
  const int wave = t >> 6;       // 8 waves
  const int i_sub = lane & 15;   // low bits -> DPP-row reduction axis
  const int oq = lane >> 4;      // o-quad in [0,4)
  const int i = i0 + i_sub;

  for (int bb = 0; bb < 2; ++bb) {
    const int b = bt * BTILE + wave * 2 + bb;

    // input row x[b,i,0..7]
    const float4 xa =
        *reinterpret_cast<const float4*>(x + ((size_t)b * NUM_IN + i) * 8);
    const float4 xb =
        *reinterpret_cast<const float4*>(x + ((size_t)b * NUM_IN + i) * 8 + 4);
    const float xd[8] = {xa.x, xa.y, xa.z, xa.w, xb.x, xb.y, xb.z, xb.w};

    // u_hat[j][o_quad] = sum_d x[d] * W[i,d,j,o4]
    float4 u[10];
#pragma unroll
    for (int j = 0; j < 10; ++j) {
      float4 acc = {0.f, 0.f, 0.f, 0.f};
#pragma unroll
      for (int d = 0; d < 8; ++d) {
        const float4 w = *reinterpret_cast<const float4*>(
            Ws + (d * 10 + j) * 256 + i_sub * 16 + oq * 4);
        acc.x += xd[d] * w.x;
        acc.y += xd[d] * w.y;
        acc.z += xd[d] * w.z;
        acc.w += xd[d] * w.w;
      }
      u[j] = acc;
    }

    // coupling coefficients
    float c[10];
    if (PASS == 0) {
#pragma unroll
      for (int j = 0; j < 10; ++j) c[j] = 0.1f;
    } else {
      float lg[10];
#pragma unroll
      for (int j = 0; j < 10; ++j) {
        const float4 vv =
            *reinterpret_cast<const float4*>(v0 + b * SLOTS + j * 16 + oq * 4);
        float p = u[j].x * vv.x + u[j].y * vv.y + u[j].z * vv.z + u[j].w * vv.w;
        p += __shfl_xor(p, 16);  // reduce over the 4 o-quad lanes
        p += __shfl_xor(p, 32);
        lg[j] = p;
      }
      if (PASS == 2) {
#pragma unroll
        for (int j = 0; j < 10; ++j) {
          const float4 vv = *reinterpret_cast<const float4*>(v1 + b * SLOTS +
                                                            j * 16 + oq * 4);
          float p =
              u[j].x * vv.x + u[j].y * vv.y + u[j].z * vv.z + u[j].w * vv.w;
          p += __shfl_xor(p, 16);
          p += __shfl_xor(p, 32);
          lg[j] += p;
        }
      }
      // softmax over j (redundant per lane, 10 values)
      float m = lg[0];
#pragma unroll
      for (int j = 1; j < 10; ++j) m = fmaxf(m, lg[j]);
      float e[10], sum = 0.f;
#pragma unroll
      for (int j = 0; j < 10; ++j) {
        e[j] = __expf(lg[j] - m);
        sum += e[j];
      }
      const float inv = 1.0f / sum;
#pragma unroll
      for (int j = 0; j < 10; ++j) c[j] = e[j] * inv;
    }

    // s_partial[j][o4] = sum_{i in chunk} c*u_hat  (DPP reduce over i_sub)
#pragma unroll
    for (int j = 0; j < 10; ++j) {
      const float sx = rowsum16(c[j] * u[j].x);
      const float sy = rowsum16(c[j] * u[j].y);
      const float sz = rowsum16(c[j] * u[j].z);
      const float sw = rowsum16(c[j] * u[j].w);
      if (i_sub == 0) {
        float* p = s_out + (size_t)b * SLOTS + j * 16 + oq * 4;
        atomicAdd(p + 0, sx);
        atomicAdd(p + 1, sy);
        atomicAdd(p + 2, sz);
        atomicAdd(p + 3, sw);
      }
    }
  }
}

// v = squash(s); optionally re-zero s for the next pass.
// NOTE: no __restrict__ here -- s_in and s_zero alias intentionally.
__global__ __launch_bounds__(192) void caps_squash(const float* s_in,
                                                   float* v_out,
                                                   float* s_zero) {
  const int b = blockIdx.x;
  const int t = threadIdx.x;
  if (t < SLOTS) {
    const float sv = s_in[(size_t)b * SLOTS + t];
    const float sq = rowsum16(sv * sv);  // j-groups of 16 lanes are row-aligned
    const float scale = sq / (1.0f + sq) * rsqrtf(sq + 1e-8f);
    v_out[(size_t)b * SLOTS + t] = sv * scale;
    if (s_zero) s_zero[(size_t)b * SLOTS + t] = 0.0f;
  }
}

extern "C" void kernel_launch(void* const* d_in, const int* in_sizes, int n_in,
                              void* d_out, int out_size, void* d_ws,
                              size_t ws_size, hipStream_t stream) {
  const float* x = (const float*)d_in[0];  // (256,1152,8)
  const float* W = (const float*)d_in[1];  // (1152,8,10,16)
  float* out = (float*)d_out;              // (256,10,16)

  float* s_buf = (float*)d_ws;             // 160 KB
  float* v0 = s_buf + BATCH * SLOTS;       // 160 KB
  float* v1 = v0 + BATCH * SLOTS;          // 160 KB

  hipMemsetAsync(s_buf, 0, (size_t)BATCH * SLOTS * sizeof(float), stream);

  const dim3 pg(NCHUNK * NBT);  // 1152 blocks
  caps_pass<0><<<pg, 512, 0, stream>>>(x, W, nullptr, nullptr, s_buf);
  caps_squash<<<BATCH, 192, 0, stream>>>(s_buf, v0, s_buf);
  caps_pass<1><<<pg, 512, 0, stream>>>(x, W, v0, nullptr, s_buf);
  caps_squash<<<BATCH, 192, 0, stream>>>(s_buf, v1, s_buf);
  caps_pass<2><<<pg, 512, 0, stream>>>(x, W, v0, v1, s_buf);
  caps_squash<<<BATCH, 192, 0, stream>>>(s_buf, out, nullptr);
}

// Round 2
// 678.236 us; speedup vs baseline: 1.0800x; 1.0800x over previous
//
#include <hip/hip_runtime.h>

// Capsule dynamic routing, MI355X (gfx950).
// Shapes: x (256,1152,8) f32, W (1152,8,10,16) f32, out v (256,10,16) f32.
// Strategy: never materialize u_hat (189MB). 3 routing passes recompute
// u_hat from LDS-staged W chunks. b-logits recomputed from saved v0/v1
// (b_iter2 = agr(v0)+agr(v1)) so no logit tensor.
// R1 -> R2: global atomics were the bottleneck (~490MB of contended RMW
// fabric traffic, VALUBusy 10%). Replaced with per-chunk partial stores
// (part[ic][b][160], 11.25 MiB ws) + fused reduce+squash kernel.

#define NUM_IN 1152
#define IN_DIM 8
#define NUM_OUT 10
#define OUT_DIM 16
#define BATCH 256
#define ICHUNK 16
#define NCHUNK (NUM_IN / ICHUNK)   // 72
#define BTILE 16
#define NBT (BATCH / BTILE)        // 16
#define SLOTS (NUM_OUT * OUT_DIM)  // 160

// Sum over the 16 contiguous lanes of a DPP "row" via row_ror rotations.
// All lanes end with the full row sum. Requires the 16-lane row active.
__device__ __forceinline__ float rowsum16(float x) {
  int v;
  v = __builtin_amdgcn_update_dpp(0, __float_as_int(x), 0x128, 0xF, 0xF, true); // ror:8
  x += __int_as_float(v);
  v = __builtin_amdgcn_update_dpp(0, __float_as_int(x), 0x124, 0xF, 0xF, true); // ror:4
  x += __int_as_float(v);
  v = __builtin_amdgcn_update_dpp(0, __float_as_int(x), 0x122, 0xF, 0xF, true); // ror:2
  x += __int_as_float(v);
  v = __builtin_amdgcn_update_dpp(0, __float_as_int(x), 0x121, 0xF, 0xF, true); // ror:1
  x += __int_as_float(v);
  return x;
}

// One routing pass. PASS=0: uniform c=0.1. PASS=1: c=softmax(agr(v0)).
// PASS=2: c=softmax(agr(v0)+agr(v1)).
// PART=true: store partial s to part[ic][b][slot] (no atomics).
// PART=false: legacy atomicAdd into s_out (ws-too-small fallback).
template <int PASS, bool PART>
__global__ __launch_bounds__(512) void caps_pass(
    const float* __restrict__ x, const float* __restrict__ W,
    const float* __restrict__ v0, const float* __restrict__ v1,
    float* __restrict__ s_out, float* __restrict__ part) {
  // W chunk for 16 input capsules, laid out [d][j][i_sub][o] so that for a
  // fixed (d,j) the wave's 64 float4 reads cover one contiguous 1KB block
  // (permuted by lane) -> conflict-free ds_read_b128.
  __shared__ float Ws[IN_DIM * NUM_OUT * ICHUNK * OUT_DIM];  // 80 KB

  const int t = threadIdx.x;
  const int ic = blockIdx.x % NCHUNK;
  const int bt = blockIdx.x / NCHUNK;
  const int i0 = ic * ICHUNK;

  // Cooperative stage: global W[(i0+i)*1280 + d*160 + j*16 + o]
  //                  -> Ws[((d*10+j)*16 + i)*16 + o], float4 granularity.
  for (int q = t; q < (ICHUNK * 1280) / 4; q += 512) {
    const int idx = q * 4;
    const int i = idx / 1280;
    const int rem = idx % 1280;          // d*160 + j*16 + o
    const float4 w =
        *reinterpret_cast<const float4*>(W + (size_t)(i0 + i) * 1280 + rem);
    const int d = rem / 160;
    const int jo = rem % 160;
    *reinterpret_cast<float4*>(Ws + (d * 10 + (jo >> 4)) * 256 + i * 16 +
                               (jo & 15)) = w;
  }
  __syncthreads();

  const int lane = t & 63;
  const int wave = t >> 6;       // 8 waves
  const int i_sub = lane & 15;   // low bits -> DPP-row reduction axis
  const int oq = lane >> 4;      // o-quad in [0,4)
  const int i = i0 + i_sub;

  for (int bb = 0; bb < 2; ++bb) {
    const int b = bt * BTILE + wave * 2 + bb;

    // input row x[b,i,0..7]
    const float4 xa =
        *reinterpret_cast<const float4*>(x + ((size_t)b * NUM_IN + i) * 8);
    const float4 xb =
        *reinterpret_cast<const float4*>(x + ((size_t)b * NUM_IN + i) * 8 + 4);
    const float xd[8] = {xa.x, xa.y, xa.z, xa.w, xb.x, xb.y, xb.z, xb.w};

    // u_hat[j][o_quad] = sum_d x[d] * W[i,d,j,o4]
    float4 u[10];
#pragma unroll
    for (int j = 0; j < 10; ++j) {
      float4 acc = {0.f, 0.f, 0.f, 0.f};
#pragma unroll
      for (int d = 0; d < 8; ++d) {
        const float4 w = *reinterpret_cast<const float4*>(
            Ws + (d * 10 + j) * 256 + i_sub * 16 + oq * 4);
        acc.x += xd[d] * w.x;
        acc.y += xd[d] * w.y;
        acc.z += xd[d] * w.z;
        acc.w += xd[d] * w.w;
      }
      u[j] = acc;
    }

    // coupling coefficients
    float c[10];
    if (PASS == 0) {
#pragma unroll
      for (int j = 0; j < 10; ++j) c[j] = 0.1f;
    } else {
      float lg[10];
#pragma unroll
      for (int j = 0; j < 10; ++j) {
        const float4 vv =
            *reinterpret_cast<const float4*>(v0 + b * SLOTS + j * 16 + oq * 4);
        float p = u[j].x * vv.x + u[j].y * vv.y + u[j].z * vv.z + u[j].w * vv.w;
        p += __shfl_xor(p, 16);  // reduce over the 4 o-quad lanes
        p += __shfl_xor(p, 32);
        lg[j] = p;
      }
      if (PASS == 2) {
#pragma unroll
        for (int j = 0; j < 10; ++j) {
          const float4 vv = *reinterpret_cast<const float4*>(v1 + b * SLOTS +
                                                            j * 16 + oq * 4);
          float p =
              u[j].x * vv.x + u[j].y * vv.y + u[j].z * vv.z + u[j].w * vv.w;
          p += __shfl_xor(p, 16);
          p += __shfl_xor(p, 32);
          lg[j] += p;
        }
      }
      // softmax over j (redundant per lane, 10 values)
      float m = lg[0];
#pragma unroll
      for (int j = 1; j < 10; ++j) m = fmaxf(m, lg[j]);
      float e[10], sum = 0.f;
#pragma unroll
      for (int j = 0; j < 10; ++j) {
        e[j] = __expf(lg[j] - m);
        sum += e[j];
      }
      const float inv = 1.0f / sum;
#pragma unroll
      for (int j = 0; j < 10; ++j) c[j] = e[j] * inv;
    }

    // s_partial[j][o4] = sum_{i in chunk} c*u_hat  (DPP reduce over i_sub)
#pragma unroll
    for (int j = 0; j < 10; ++j) {
      const float sx = rowsum16(c[j] * u[j].x);
      const float sy = rowsum16(c[j] * u[j].y);
      const float sz = rowsum16(c[j] * u[j].z);
      const float sw = rowsum16(c[j] * u[j].w);
      if (i_sub == 0) {
        if (PART) {
          // 4 lanes (oq 0..3) store one float4 each: 64B contiguous per j.
          const float4 sv = {sx, sy, sz, sw};
          *reinterpret_cast<float4*>(part + ((size_t)ic * BATCH + b) * SLOTS +
                                     j * 16 + oq * 4) = sv;
        } else {
          float* p = s_out + (size_t)b * SLOTS + j * 16 + oq * 4;
          atomicAdd(p + 0, sx);
          atomicAdd(p + 1, sy);
          atomicAdd(p + 2, sz);
          atomicAdd(p + 3, sw);
        }
      }
    }
  }
}

// v = squash(sum_ic part[ic][b][:]). One block per batch element.
__global__ __launch_bounds__(192) void caps_reduce_squash(
    const float* __restrict__ part, float* __restrict__ v_out) {
  const int b = blockIdx.x;
  const int t = threadIdx.x;
  if (t < SLOTS) {
    float sv = 0.0f;
#pragma unroll 8
    for (int ic = 0; ic < NCHUNK; ++ic)
      sv += part[((size_t)ic * BATCH + b) * SLOTS + t];
    const float sq = rowsum16(sv * sv);  // 16-lane rows == one j each
    const float scale = sq / (1.0f + sq) * rsqrtf(sq + 1e-8f);
    v_out[(size_t)b * SLOTS + t] = sv * scale;
  }
}

// Fallback squash for the atomic path (s_in/s_zero alias intentionally).
__global__ __launch_bounds__(192) void caps_squash(const float* s_in,
                                                   float* v_out,
                                                   float* s_zero) {
  const int b = blockIdx.x;
  const int t = threadIdx.x;
  if (t < SLOTS) {
    const float sv = s_in[(size_t)b * SLOTS + t];
    const float sq = rowsum16(sv * sv);
    const float scale = sq / (1.0f + sq) * rsqrtf(sq + 1e-8f);
    v_out[(size_t)b * SLOTS + t] = sv * scale;
    if (s_zero) s_zero[(size_t)b * SLOTS + t] = 0.0f;
  }
}

extern "C" void kernel_launch(void* const* d_in, const int* in_sizes, int n_in,
                              void* d_out, int out_size, void* d_ws,
                              size_t ws_size, hipStream_t stream) {
  const float* x = (const float*)d_in[0];  // (256,1152,8)
  const float* W = (const float*)d_in[1];  // (1152,8,10,16)
  float* out = (float*)d_out;              // (256,10,16)

  const size_t part_elems = (size_t)NCHUNK * BATCH * SLOTS;  // 2.95M
  const size_t need = (part_elems + 2 * BATCH * SLOTS) * sizeof(float);
  const dim3 pg(NCHUNK * NBT);  // 1152 blocks

  if (ws_size >= need) {
    float* part = (float*)d_ws;                // 11.25 MiB
    float* v0 = part + part_elems;             // 160 KB
    float* v1 = v0 + BATCH * SLOTS;            // 160 KB
    caps_pass<0, true><<<pg, 512, 0, stream>>>(x, W, nullptr, nullptr,
                                               nullptr, part);
    caps_reduce_squash<<<BATCH, 192, 0, stream>>>(part, v0);
    caps_pass<1, true><<<pg, 512, 0, stream>>>(x, W, v0, nullptr, nullptr,
                                               part);
    caps_reduce_squash<<<BATCH, 192, 0, stream>>>(part, v1);
    caps_pass<2, true><<<pg, 512, 0, stream>>>(x, W, v0, v1, nullptr, part);
    caps_reduce_squash<<<BATCH, 192, 0, stream>>>(part, out);
  } else {
    // Legacy atomic path (proven correct in R1).
    float* s_buf = (float*)d_ws;
    float* v0 = s_buf + BATCH * SLOTS;
    float* v1 = v0 + BATCH * SLOTS;
    hipMemsetAsync(s_buf, 0, (size_t)BATCH * SLOTS * sizeof(float), stream);
    caps_pass<0, false><<<pg, 512, 0, stream>>>(x, W, nullptr, nullptr, s_buf,
                                                nullptr);
    caps_squash<<<BATCH, 192, 0, stream>>>(s_buf, v0, s_buf);
    caps_pass<1, false><<<pg, 512, 0, stream>>>(x, W, v0, nullptr, s_buf,
                                                nullptr);
    caps_squash<<<BATCH, 192, 0, stream>>>(s_buf, v1, s_buf);
    caps_pass<2, false><<<pg, 512, 0, stream>>>(x, W, v0, v1, s_buf, nullptr);
    caps_squash<<<BATCH, 192, 0, stream>>>(s_buf, out, nullptr);
  }
}

// Round 3
// 198.282 us; speedup vs baseline: 3.6940x; 3.4206x over previous
//
#include <hip/hip_runtime.h>

// Capsule dynamic routing, MI355X (gfx950).
// Shapes: x (256,1152,8) f32, W (1152,8,10,16) f32, out v (256,10,16) f32.
// R2 -> R3: R2's 390MB fetch + 382MB write per pass was SCRATCH SPILL
// traffic (u[10] float4 live across softmax at VGPR cap 128). Restructured:
// phase A streams j to build logits only (lg[10]); phase C recomputes u_j
// per j from LDS (VALU was 90% idle -> recompute is free). Both b's of a
// wave processed jointly so each LDS W read serves 2 batch elements.
// LDS layout now conflict-free: for fixed (d,j), lane l reads 16B at
// Ws[(d*10+j)*256 + l*4] -- a contiguous 1KB block per wave instruction.

#define NUM_IN 1152
#define IN_DIM 8
#define NUM_OUT 10
#define OUT_DIM 16
#define BATCH 256
#define ICHUNK 16
#define NCHUNK (NUM_IN / ICHUNK)   // 72
#define BTILE 16
#define NBT (BATCH / BTILE)        // 16
#define SLOTS (NUM_OUT * OUT_DIM)  // 160

// Sum over the 16 contiguous lanes of a DPP "row" via row_ror rotations.
// All lanes end with the full row sum.
__device__ __forceinline__ float rowsum16(float x) {
  int v;
  v = __builtin_amdgcn_update_dpp(0, __float_as_int(x), 0x128, 0xF, 0xF, true); // ror:8
  x += __int_as_float(v);
  v = __builtin_amdgcn_update_dpp(0, __float_as_int(x), 0x124, 0xF, 0xF, true); // ror:4
  x += __int_as_float(v);
  v = __builtin_amdgcn_update_dpp(0, __float_as_int(x), 0x122, 0xF, 0xF, true); // ror:2
  x += __int_as_float(v);
  v = __builtin_amdgcn_update_dpp(0, __float_as_int(x), 0x121, 0xF, 0xF, true); // ror:1
  x += __int_as_float(v);
  return x;
}

// One routing pass. PASS=0: uniform c=0.1. PASS=1: c=softmax(agr(v0)).
// PASS=2: c=softmax(agr(v0)+agr(v1)).
// PART=true: store partial s to part[ic][b][slot]. PART=false: atomicAdd.
template <int PASS, bool PART>
__global__ __launch_bounds__(512) void caps_pass(
    const float* __restrict__ x, const float* __restrict__ W,
    const float* __restrict__ v0, const float* __restrict__ v1,
    float* __restrict__ s_out, float* __restrict__ part) {
  // Ws element (i_sub, d, j, o=oq*4+m) at (d*10+j)*256 + oq*64 + i_sub*4 + m.
  // => for fixed (d,j), lane (oq*16+i_sub) reads float4 at lane*16 bytes.
  __shared__ float Ws[IN_DIM * NUM_OUT * ICHUNK * OUT_DIM];  // 80 KB

  const int t = threadIdx.x;
  const int ic = blockIdx.x % NCHUNK;
  const int bt = blockIdx.x / NCHUNK;
  const int i0 = ic * ICHUNK;

  // Cooperative stage, coalesced global float4 reads.
  // global (i,d,j,4k+m) -> Ws[(d*10+j)*256 + k*64 + i*4 + m]
  for (int q = t; q < (ICHUNK * 1280) / 4; q += 512) {
    const int idx = q * 4;
    const int i = idx / 1280;
    const int rem = idx - i * 1280;  // d*160 + j*16 + 4k
    const int d = rem / 160;
    const int jo = rem - d * 160;
    const int j = jo >> 4;
    const int k = (jo & 15) >> 2;
    const float4 w =
        *reinterpret_cast<const float4*>(W + (size_t)(i0 + i) * 1280 + rem);
    *reinterpret_cast<float4*>(Ws + (d * 10 + j) * 256 + k * 64 + i * 4) = w;
  }
  __syncthreads();

  const int lane = t & 63;
  const int wave = t >> 6;       // 8 waves
  const int i_sub = lane & 15;   // DPP-row reduction axis
  const int oq = lane >> 4;      // o-quad in [0,4)
  const float* wsl = Ws + lane * 4;

  const int b0 = bt * BTILE + wave * 2;
  const int b1 = b0 + 1;

  // input rows x[b,i0+i_sub,0..7] for both b's
  float xd0[8], xd1[8];
  {
    const float* p0 = x + ((size_t)b0 * NUM_IN + i0 + i_sub) * 8;
    const float* p1 = x + ((size_t)b1 * NUM_IN + i0 + i_sub) * 8;
    const float4 a0 = *reinterpret_cast<const float4*>(p0);
    const float4 a1 = *reinterpret_cast<const float4*>(p0 + 4);
    const float4 a2 = *reinterpret_cast<const float4*>(p1);
    const float4 a3 = *reinterpret_cast<const float4*>(p1 + 4);
    xd0[0] = a0.x; xd0[1] = a0.y; xd0[2] = a0.z; xd0[3] = a0.w;
    xd0[4] = a1.x; xd0[5] = a1.y; xd0[6] = a1.z; xd0[7] = a1.w;
    xd1[0] = a2.x; xd1[1] = a2.y; xd1[2] = a2.z; xd1[3] = a2.w;
    xd1[4] = a3.x; xd1[5] = a3.y; xd1[6] = a3.z; xd1[7] = a3.w;
  }

  float c0[10], c1[10];
  if (PASS == 0) {
#pragma unroll
    for (int j = 0; j < 10; ++j) { c0[j] = 0.1f; c1[j] = 0.1f; }
  } else {
    // Phase A: logits. u_j lives only inside the j iteration.
#pragma unroll
    for (int j = 0; j < 10; ++j) {
      float4 a0 = {0.f, 0.f, 0.f, 0.f}, a1 = {0.f, 0.f, 0.f, 0.f};
#pragma unroll
      for (int d = 0; d < 8; ++d) {
        const float4 w = *reinterpret_cast<const float4*>(wsl + (d * 10 + j) * 256);
        a0.x = fmaf(xd0[d], w.x, a0.x); a0.y = fmaf(xd0[d], w.y, a0.y);
        a0.z = fmaf(xd0[d], w.z, a0.z); a0.w = fmaf(xd0[d], w.w, a0.w);
        a1.x = fmaf(xd1[d], w.x, a1.x); a1.y = fmaf(xd1[d], w.y, a1.y);
        a1.z = fmaf(xd1[d], w.z, a1.z); a1.w = fmaf(xd1[d], w.w, a1.w);
      }
      const float4 p0 = *reinterpret_cast<const float4*>(v0 + b0 * SLOTS + j * 16 + oq * 4);
      const float4 p1 = *reinterpret_cast<const float4*>(v0 + b1 * SLOTS + j * 16 + oq * 4);
      float l0 = a0.x * p0.x + a0.y * p0.y + a0.z * p0.z + a0.w * p0.w;
      float l1 = a1.x * p1.x + a1.y * p1.y + a1.z * p1.z + a1.w * p1.w;
      if (PASS == 2) {
        const float4 q0 = *reinterpret_cast<const float4*>(v1 + b0 * SLOTS + j * 16 + oq * 4);
        const float4 q1 = *reinterpret_cast<const float4*>(v1 + b1 * SLOTS + j * 16 + oq * 4);
        l0 += a0.x * q0.x + a0.y * q0.y + a0.z * q0.z + a0.w * q0.w;
        l1 += a1.x * q1.x + a1.y * q1.y + a1.z * q1.z + a1.w * q1.w;
      }
      l0 += __shfl_xor(l0, 16); l0 += __shfl_xor(l0, 32);
      l1 += __shfl_xor(l1, 16); l1 += __shfl_xor(l1, 32);
      c0[j] = l0; c1[j] = l1;  // raw logits for now
    }
    // softmax over j, in place (10 values per b, per lane)
    float m0 = c0[0], m1 = c1[0];
#pragma unroll
    for (int j = 1; j < 10; ++j) { m0 = fmaxf(m0, c0[j]); m1 = fmaxf(m1, c1[j]); }
    float s0 = 0.f, s1 = 0.f;
#pragma unroll
    for (int j = 0; j < 10; ++j) {
      c0[j] = __expf(c0[j] - m0); s0 += c0[j];
      c1[j] = __expf(c1[j] - m1); s1 += c1[j];
    }
    const float r0 = 1.0f / s0, r1 = 1.0f / s1;
#pragma unroll
    for (int j = 0; j < 10; ++j) { c0[j] *= r0; c1[j] *= r1; }
  }

  // Phase C: recompute u_j, weight by c_j, reduce over i_sub, store.
#pragma unroll
  for (int j = 0; j < 10; ++j) {
    float4 a0 = {0.f, 0.f, 0.f, 0.f}, a1 = {0.f, 0.f, 0.f, 0.f};
#pragma unroll
    for (int d = 0; d < 8; ++d) {
      const float4 w = *reinterpret_cast<const float4*>(wsl + (d * 10 + j) * 256);
      a0.x = fmaf(xd0[d], w.x, a0.x); a0.y = fmaf(xd0[d], w.y, a0.y);
      a0.z = fmaf(xd0[d], w.z, a0.z); a0.w = fmaf(xd0[d], w.w, a0.w);
      a1.x = fmaf(xd1[d], w.x, a1.x); a1.y = fmaf(xd1[d], w.y, a1.y);
      a1.z = fmaf(xd1[d], w.z, a1.z); a1.w = fmaf(xd1[d], w.w, a1.w);
    }
    const float sx0 = rowsum16(c0[j] * a0.x);
    const float sy0 = rowsum16(c0[j] * a0.y);
    const float sz0 = rowsum16(c0[j] * a0.z);
    const float sw0 = rowsum16(c0[j] * a0.w);
    const float sx1 = rowsum16(c1[j] * a1.x);
    const float sy1 = rowsum16(c1[j] * a1.y);
    const float sz1 = rowsum16(c1[j] * a1.z);
    const float sw1 = rowsum16(c1[j] * a1.w);
    if (i_sub == 0) {
      if (PART) {
        const float4 v0s = {sx0, sy0, sz0, sw0};
        const float4 v1s = {sx1, sy1, sz1, sw1};
        *reinterpret_cast<float4*>(part + ((size_t)ic * BATCH + b0) * SLOTS +
                                   j * 16 + oq * 4) = v0s;
        *reinterpret_cast<float4*>(part + ((size_t)ic * BATCH + b1) * SLOTS +
                                   j * 16 + oq * 4) = v1s;
      } else {
        float* p0 = s_out + (size_t)b0 * SLOTS + j * 16 + oq * 4;
        float* p1 = s_out + (size_t)b1 * SLOTS + j * 16 + oq * 4;
        atomicAdd(p0 + 0, sx0); atomicAdd(p0 + 1, sy0);
        atomicAdd(p0 + 2, sz0); atomicAdd(p0 + 3, sw0);
        atomicAdd(p1 + 0, sx1); atomicAdd(p1 + 1, sy1);
        atomicAdd(p1 + 2, sz1); atomicAdd(p1 + 3, sw1);
      }
    }
  }
}

// v = squash(sum_ic part[ic][b][:]). One block per batch element.
__global__ __launch_bounds__(192) void caps_reduce_squash(
    const float* __restrict__ part, float* __restrict__ v_out) {
  const int b = blockIdx.x;
  const int t = threadIdx.x;
  if (t < SLOTS) {
    float sv = 0.0f;
#pragma unroll 8
    for (int ic = 0; ic < NCHUNK; ++ic)
      sv += part[((size_t)ic * BATCH + b) * SLOTS + t];
    const float sq = rowsum16(sv * sv);  // 16-lane rows == one j each
    const float scale = sq / (1.0f + sq) * rsqrtf(sq + 1e-8f);
    v_out[(size_t)b * SLOTS + t] = sv * scale;
  }
}

// Fallback squash for the atomic path (s_in/s_zero alias intentionally).
__global__ __launch_bounds__(192) void caps_squash(const float* s_in,
                                                   float* v_out,
                                                   float* s_zero) {
  const int b = blockIdx.x;
  const int t = threadIdx.x;
  if (t < SLOTS) {
    const float sv = s_in[(size_t)b * SLOTS + t];
    const float sq = rowsum16(sv * sv);
    const float scale = sq / (1.0f + sq) * rsqrtf(sq + 1e-8f);
    v_out[(size_t)b * SLOTS + t] = sv * scale;
    if (s_zero) s_zero[(size_t)b * SLOTS + t] = 0.0f;
  }
}

extern "C" void kernel_launch(void* const* d_in, const int* in_sizes, int n_in,
                              void* d_out, int out_size, void* d_ws,
                              size_t ws_size, hipStream_t stream) {
  const float* x = (const float*)d_in[0];  // (256,1152,8)
  const float* W = (const float*)d_in[1];  // (1152,8,10,16)
  float* out = (float*)d_out;              // (256,10,16)

  const size_t part_elems = (size_t)NCHUNK * BATCH * SLOTS;  // 2.95M
  const size_t need = (part_elems + 2 * BATCH * SLOTS) * sizeof(float);
  const dim3 pg(NCHUNK * NBT);  // 1152 blocks

  if (ws_size >= need) {
    float* part = (float*)d_ws;                // 11.25 MiB
    float* v0 = part + part_elems;             // 160 KB
    float* v1 = v0 + BATCH * SLOTS;            // 160 KB
    caps_pass<0, true><<<pg, 512, 0, stream>>>(x, W, nullptr, nullptr,
                                               nullptr, part);
    caps_reduce_squash<<<BATCH, 192, 0, stream>>>(part, v0);
    caps_pass<1, true><<<pg, 512, 0, stream>>>(x, W, v0, nullptr, nullptr,
                                               part);
    caps_reduce_squash<<<BATCH, 192, 0, stream>>>(part, v1);
    caps_pass<2, true><<<pg, 512, 0, stream>>>(x, W, v0, v1, nullptr, part);
    caps_reduce_squash<<<BATCH, 192, 0, stream>>>(part, out);
  } else {
    // Legacy atomic path.
    float* s_buf = (float*)d_ws;
    float* v0 = s_buf + BATCH * SLOTS;
    float* v1 = v0 + BATCH * SLOTS;
    hipMemsetAsync(s_buf, 0, (size_t)BATCH * SLOTS * sizeof(float), stream);
    caps_pass<0, false><<<pg, 512, 0, stream>>>(x, W, nullptr, nullptr, s_buf,
                                                nullptr);
    caps_squash<<<BATCH, 192, 0, stream>>>(s_buf, v0, s_buf);
    caps_pass<1, false><<<pg, 512, 0, stream>>>(x, W, v0, nullptr, s_buf,
                                                nullptr);
    caps_squash<<<BATCH, 192, 0, stream>>>(s_buf, v1, s_buf);
    caps_pass<2, false><<<pg, 512, 0, stream>>>(x, W, v0, v1, s_buf, nullptr);
    caps_squash<<<BATCH, 192, 0, stream>>>(s_buf, out, nullptr);
  }
}